// Round 1
// baseline (716.363 us; speedup 1.0000x reference)
//
#include <hip/hip_runtime.h>
#include <math.h>

#define T_DIM   2048
#define B_DIM   128
#define E_DIM   512
#define NSPLIT  32
#define TC      (T_DIM / NSPLIT)    // 64 timesteps per (block, wave)
#define GB      8                   // batches per block: one per wave -> 16KB contiguous/t
#define ROWS    4                   // t-rows batched per compute step

typedef float floatx4 __attribute__((ext_vector_type(4)));

__device__ __forceinline__ float wave_reduce_sum(float v) {
    v += __shfl_xor(v, 1,  64);
    v += __shfl_xor(v, 2,  64);
    v += __shfl_xor(v, 4,  64);
    v += __shfl_xor(v, 8,  64);
    v += __shfl_xor(v, 16, 64);
    v += __shfl_xor(v, 32, 64);
    return v;
}

__device__ __forceinline__ float4 wave_reduce_sum4(float4 v) {
    #pragma unroll
    for (int mask = 1; mask < 64; mask <<= 1) {
        v.x += __shfl_xor(v.x, mask, 64);
        v.y += __shfl_xor(v.y, mask, 64);
        v.z += __shfl_xor(v.z, mask, 64);
        v.w += __shfl_xor(v.w, mask, 64);
    }
    return v;
}

// Non-temporal 16B load via native ext-vector type (builtin rejects HIP_vector_type)
__device__ __forceinline__ floatx4 nt_load4(const float* p) {
    return __builtin_nontemporal_load((const floatx4*)p);
}

// Kernel A: xp[b,e] = sum_k x[b,k] * W[e,k] + bias[e]   (unchanged)
__global__ __launch_bounds__(256) void proj_kernel(
    const float* __restrict__ x, const float* __restrict__ W,
    const float* __restrict__ bias, float* __restrict__ xp,
    float* __restrict__ out)
{
    const int b      = blockIdx.x;
    const int echunk = blockIdx.y;     // 0..3
    const int tid    = threadIdx.x;
    const int lane   = tid & 63;
    const int wave   = tid >> 6;

    const float4* x4 = (const float4*)(x + (size_t)b * E_DIM);
    const float4 xq0 = x4[lane];
    const float4 xq1 = x4[64 + lane];

    const int ebase = echunk * 128;
    for (int e = ebase + wave; e < ebase + 128; e += 4) {
        const float4* w4 = (const float4*)(W + (size_t)e * E_DIM);
        const float4 w0 = w4[lane];
        const float4 w1 = w4[64 + lane];
        float p = w0.x*xq0.x + w0.y*xq0.y + w0.z*xq0.z + w0.w*xq0.w;
        p      += w1.x*xq1.x + w1.y*xq1.y + w1.z*xq1.z + w1.w*xq1.w;
        p = wave_reduce_sum(p);
        if (lane == 0) {
            float v = p + bias[e];
            xp[(size_t)b * E_DIM + e] = v;
            out[(size_t)b * (2 * E_DIM) + e] = v;
        }
    }
}

__device__ __forceinline__ void load_rows(
    const float* __restrict__ base, size_t row_stride, int i, int lane,
    floatx4 (&e0)[ROWS], floatx4 (&e1)[ROWS])
{
    #pragma unroll
    for (int r = 0; r < ROWS; ++r) {
        const float* erow = base + (size_t)(i + r) * row_stride;
        e0[r] = nt_load4(erow + 4 * lane);
        e1[r] = nt_load4(erow + 4 * (64 + lane));
    }
}

__device__ __forceinline__ void compute_rows(
    const floatx4 (&e0)[ROWS], const floatx4 (&e1)[ROWS],
    const float4 xq0, const float4 xq1,
    float& m, float& l, float4& a0, float4& a1)
{
    float t[ROWS];
    #pragma unroll
    for (int r = 0; r < ROWS; ++r) {
        t[r]  = e0[r].x*xq0.x + e0[r].y*xq0.y + e0[r].z*xq0.z + e0[r].w*xq0.w;
        t[r] += e1[r].x*xq1.x + e1[r].y*xq1.y + e1[r].z*xq1.z + e1[r].w*xq1.w;
    }
    float4 d = make_float4(t[0], t[1], t[2], t[3]);
    d = wave_reduce_sum4(d);

    const float mrow  = fmaxf(fmaxf(d.x, d.y), fmaxf(d.z, d.w));
    const float m_new = fmaxf(m, mrow);
    const float scale = __expf(m - m_new);
    const float p0 = __expf(d.x - m_new);
    const float p1 = __expf(d.y - m_new);
    const float p2 = __expf(d.z - m_new);
    const float p3 = __expf(d.w - m_new);
    l = l * scale + (p0 + p1 + p2 + p3);

    a0.x = a0.x*scale + p0*e0[0].x + p1*e0[1].x + p2*e0[2].x + p3*e0[3].x;
    a0.y = a0.y*scale + p0*e0[0].y + p1*e0[1].y + p2*e0[2].y + p3*e0[3].y;
    a0.z = a0.z*scale + p0*e0[0].z + p1*e0[1].z + p2*e0[2].z + p3*e0[3].z;
    a0.w = a0.w*scale + p0*e0[0].w + p1*e0[1].w + p2*e0[2].w + p3*e0[3].w;
    a1.x = a1.x*scale + p0*e1[0].x + p1*e1[1].x + p2*e1[2].x + p3*e1[3].x;
    a1.y = a1.y*scale + p0*e1[0].y + p1*e1[1].y + p2*e1[2].y + p3*e1[3].y;
    a1.z = a1.z*scale + p0*e1[0].z + p1*e1[1].z + p2*e1[2].z + p3*e1[3].z;
    a1.w = a1.w*scale + p0*e1[0].w + p1*e1[1].w + p2*e1[2].w + p3*e1[3].w;
    m = m_new;
}

// Kernel B: flash-decode partials, b-grouped blocks.
// grid (B/GB, NSPLIT), 512 threads (8 waves). Wave w owns b = bg*GB + w; the
// 8 waves sweep the same t-range in lockstep, so each t-step reads a
// CONTIGUOUS 16KB chunk enc[t, b0:b0+8, :] instead of 8 isolated 2KB rows
// at 256KB stride (DRAM row-buffer locality). Register ping-pong prefetch
// overlaps next-batch loads with current-batch softmax/acc.
__global__ __launch_bounds__(512, 4) void attn_partial_kernel(
    const float* __restrict__ enc, const float* __restrict__ xp,
    float* __restrict__ m_part, float* __restrict__ l_part,
    float* __restrict__ acc_part)
{
    const int bg   = blockIdx.x;        // 0..15
    const int s    = blockIdx.y;        // 0..31
    const int tid  = threadIdx.x;
    const int lane = tid & 63;
    const int wave = tid >> 6;          // 0..7
    const int b    = bg * GB + wave;

    const float4* xp4 = (const float4*)(xp + (size_t)b * E_DIM);
    const float4 xq0 = xp4[lane];
    const float4 xq1 = xp4[64 + lane];

    float m = -INFINITY;
    float l = 0.0f;
    float4 a0 = make_float4(0.f, 0.f, 0.f, 0.f);
    float4 a1 = make_float4(0.f, 0.f, 0.f, 0.f);

    const size_t row_stride = (size_t)B_DIM * E_DIM;   // floats between t's
    const float* base = enc + ((size_t)(s * TC) * B_DIM + b) * E_DIM;

    floatx4 ea0[ROWS], ea1[ROWS];
    floatx4 eb0[ROWS], eb1[ROWS];

    load_rows(base, row_stride, 0, lane, ea0, ea1);

    #pragma unroll 1
    for (int i = 0; i < TC; i += 2 * ROWS) {
        load_rows(base, row_stride, i + ROWS, lane, eb0, eb1);
        compute_rows(ea0, ea1, xq0, xq1, m, l, a0, a1);
        if (i + 2 * ROWS < TC)
            load_rows(base, row_stride, i + 2 * ROWS, lane, ea0, ea1);
        compute_rows(eb0, eb1, xq0, xq1, m, l, a0, a1);
        __syncthreads();   // keep the 8 waves' streams adjacent in memory
    }

    // Each wave owns a full (b, s) partial: write directly, no LDS merge.
    const int pid = b * NSPLIT + s;
    if (lane == 0) {
        m_part[pid] = m;
        l_part[pid] = l;
    }
    float4* dst = (float4*)(acc_part + (size_t)pid * E_DIM);
    dst[lane]      = a0;
    dst[64 + lane] = a1;
}

// Kernel C: merge NSPLIT partials per b, write context to out[:, 512:1024].
__global__ __launch_bounds__(128) void combine_kernel(
    const float* __restrict__ m_part, const float* __restrict__ l_part,
    const float* __restrict__ acc_part, float* __restrict__ out)
{
    const int b   = blockIdx.x;
    const int tid = threadIdx.x;

    float M = -INFINITY;
    for (int s = 0; s < NSPLIT; ++s) M = fmaxf(M, m_part[b * NSPLIT + s]);

    float L = 0.f;
    float4 sum = make_float4(0.f, 0.f, 0.f, 0.f);
    for (int s = 0; s < NSPLIT; ++s) {
        const float wi = __expf(m_part[b * NSPLIT + s] - M);
        L += wi * l_part[b * NSPLIT + s];
        const float4 v = ((const float4*)(acc_part + (size_t)(b * NSPLIT + s) * E_DIM))[tid];
        sum.x += wi * v.x; sum.y += wi * v.y;
        sum.z += wi * v.z; sum.w += wi * v.w;
    }
    const float inv = 1.0f / L;
    const float4 r = make_float4(sum.x*inv, sum.y*inv, sum.z*inv, sum.w*inv);
    ((float4*)(out + (size_t)b * (2 * E_DIM) + E_DIM))[tid] = r;
}

extern "C" void kernel_launch(void* const* d_in, const int* in_sizes, int n_in,
                              void* d_out, int out_size, void* d_ws, size_t ws_size,
                              hipStream_t stream) {
    (void)in_sizes; (void)n_in; (void)out_size; (void)ws_size;
    const float* x    = (const float*)d_in[0];   // [B, 512]
    const float* enc  = (const float*)d_in[1];   // [T, B, 512]
    const float* W    = (const float*)d_in[2];   // [512, 512]
    const float* bias = (const float*)d_in[3];   // [512]
    float* out = (float*)d_out;                  // [B, 1024]

    float* ws       = (float*)d_ws;
    float* xp       = ws;                         // 65536 floats
    float* m_part   = ws + 65536;                 // B*NSPLIT = 4096
    float* l_part   = ws + 65536 + 4096;          // 4096
    float* acc_part = ws + 65536 + 8192;          // B*NSPLIT*E = 2M floats

    proj_kernel<<<dim3(B_DIM, 4), 256, 0, stream>>>(x, W, bias, xp, out);
    attn_partial_kernel<<<dim3(B_DIM / GB, NSPLIT), 512, 0, stream>>>(enc, xp, m_part, l_part, acc_part);
    combine_kernel<<<B_DIM, 128, 0, stream>>>(m_part, l_part, acc_part, out);
}